// Round 7
// baseline (96.322 us; speedup 1.0000x reference)
//
#include <hip/hip_runtime.h>
#include <hip/hip_bf16.h>

// MiniBatchDiscrimination via bf16 MFMA (gfx950) — single fused kernel.
// x: [32,16,16,256] f32, T: [256,64,8] f32, out: [32,16,16,320] f32.
// Grid 1024 = (pixel, t-quarter), 256 threads, 4 blocks/CU.
//   Phase 0: each wave gathers its 2 t-tiles of T from global (L2-resident)
//            into register MFMA B-fragments (no d_ws, no pack kernel).
//   Phase 1: stage x -> LDS A-frags (bf16) + f32 passthrough of this quarter.
//   Phase 2: MFMA 16x16x32 (32/wave).
//   Phase 3: park M quarter bf16 in LDS, pairwise exp(-L1), coalesced stores.

namespace {
constexpr int kN = 32;
constexpr int kHW = 256;
constexpr int kF = 256;          // GEMM K
constexpr int kOutRow = 320;
constexpr int kMstride = 136;    // ushorts/row: 128 + 8 pad (272 B, 16B-aligned)
constexpr int kOstride = 24;     // floats/row in obuf
}

using frag_ab = __attribute__((ext_vector_type(8))) short;   // 8 bf16
using frag_cd = __attribute__((ext_vector_type(4))) float;   // 4 f32

__device__ inline unsigned short f2bf(float f) {
  union { __hip_bfloat16 h; unsigned short u; } c;
  c.h = __float2bfloat16(f);
  return c.u;
}

__device__ inline void unpack8(const uint4& m, float* f) {
  f[0] = __uint_as_float(m.x << 16);  f[1] = __uint_as_float(m.x & 0xffff0000u);
  f[2] = __uint_as_float(m.y << 16);  f[3] = __uint_as_float(m.y & 0xffff0000u);
  f[4] = __uint_as_float(m.z << 16);  f[5] = __uint_as_float(m.z & 0xffff0000u);
  f[6] = __uint_as_float(m.w << 16);  f[7] = __uint_as_float(m.w & 0xffff0000u);
}

__global__ __launch_bounds__(256, 4)
void mbd_fused(const float* __restrict__ x, const float* __restrict__ T,
               float* __restrict__ out) {
  __shared__ uint4 Afrag[2 * 8 * 64];                           // 16 KB
  __shared__ __align__(16) unsigned short Mlds[kN * kMstride];  // 8.7 KB
  __shared__ float obuf[kN * kOstride];                         // 3 KB
  const int hw = blockIdx.x & (kHW - 1);
  const int qg = blockIdx.x >> 8;          // t-quarter 0..3 (16 b's, 128 t-cols)
  const int tid = threadIdx.x;
  const int l = tid & 63, w = tid >> 6;    // 4 waves

  // Phase 0: gather this wave's B-fragments straight from T (L2-resident).
  // Lane l, t-tile tT, k-tile kt: col = tT*16 + (l&15), k = kt*32 + (l>>4)*8 + j.
  // A 64-lane dword gather touches 4 rows x 16 cols = 4 cache lines: 100% eff.
  uint4 bfr[2][8];
#pragma unroll
  for (int q = 0; q < 2; ++q) {
    const int col = (qg * 8 + w * 2 + q) * 16 + (l & 15);
#pragma unroll
    for (int kt = 0; kt < 8; ++kt) {
      const float* Tp = T + (size_t)(kt * 32 + (l >> 4) * 8) * 512 + col;
      unsigned p[4];
#pragma unroll
      for (int jj = 0; jj < 4; ++jj) {
        float a = Tp[(size_t)(jj * 2) * 512];
        float b = Tp[(size_t)(jj * 2 + 1) * 512];
        p[jj] = (unsigned)f2bf(a) | ((unsigned)f2bf(b) << 16);
      }
      bfr[q][kt] = make_uint4(p[0], p[1], p[2], p[3]);
    }
  }

  // Phase 1: stage x -> A-frags (bf16) + passthrough this quarter's features.
  const float4* x4 = (const float4*)x;
  float4* out4 = (float4*)out;
#pragma unroll
  for (int s = 0; s < 4; ++s) {
    const int task = tid + s * 256;        // 1024 tasks: 32 n x 32 k-groups
    const int n = task >> 5;
    const int k8 = task & 31;              // group of 8 features
    const size_t xb = (size_t)n * (kHW * kF / 4) + (size_t)hw * (kF / 4) + k8 * 2;
    float4 v0 = x4[xb];
    float4 v1 = x4[xb + 1];
    if ((k8 >> 3) == qg) {                 // this block's quarter of features
      const size_t ob = (size_t)(n * kHW + hw) * (kOutRow / 4) + k8 * 2;
      out4[ob] = v0;
      out4[ob + 1] = v1;
    }
    uint4 p;
    p.x = (unsigned)f2bf(v0.x) | ((unsigned)f2bf(v0.y) << 16);
    p.y = (unsigned)f2bf(v0.z) | ((unsigned)f2bf(v0.w) << 16);
    p.z = (unsigned)f2bf(v1.x) | ((unsigned)f2bf(v1.y) << 16);
    p.w = (unsigned)f2bf(v1.z) | ((unsigned)f2bf(v1.w) << 16);
    const int rt = n >> 4, kt = k8 >> 2, ln = (n & 15) | ((k8 & 3) << 4);
    Afrag[(rt * 8 + kt) * 64 + ln] = p;
  }
  __syncthreads();

  // Phase 2: MFMA GEMM; wave w owns t-tiles qg*8 + {2w, 2w+1}.
  frag_cd acc[2][2] = {};                  // [q][rt]
#pragma unroll
  for (int kt = 0; kt < 8; ++kt) {
    uint4 a0 = Afrag[(0 * 8 + kt) * 64 + l];
    uint4 a1 = Afrag[(1 * 8 + kt) * 64 + l];
    frag_ab af0 = __builtin_bit_cast(frag_ab, a0);
    frag_ab af1 = __builtin_bit_cast(frag_ab, a1);
#pragma unroll
    for (int q = 0; q < 2; ++q) {
      frag_ab bf = __builtin_bit_cast(frag_ab, bfr[q][kt]);
      acc[q][0] = __builtin_amdgcn_mfma_f32_16x16x32_bf16(af0, bf, acc[q][0], 0, 0, 0);
      acc[q][1] = __builtin_amdgcn_mfma_f32_16x16x32_bf16(af1, bf, acc[q][1], 0, 0, 0);
    }
  }

  // Phase 3a: park M quarter (bf16). C/D: col = l&15, row = (l>>4)*4 + r.
#pragma unroll
  for (int q = 0; q < 2; ++q)
#pragma unroll
    for (int rt = 0; rt < 2; ++rt)
#pragma unroll
      for (int r = 0; r < 4; ++r) {
        const int n = rt * 16 + (l >> 4) * 4 + r;
        const int t = (w * 2 + q) * 16 + (l & 15);  // local col 0..127
        Mlds[n * kMstride + t] = f2bf(acc[q][rt][r]);
      }
  __syncthreads();

  // Phase 3b: pairwise exp(-L1). Thread: local b = tid>>4 (0..15), i in {i0,i0+1}.
  const int b = tid >> 4;
  const int i0 = (tid & 15) * 2;
  float mi[2][8];
#pragma unroll
  for (int ii = 0; ii < 2; ++ii) {
    uint4 m = *(const uint4*)&Mlds[(i0 + ii) * kMstride + b * 8];
    unpack8(m, mi[ii]);
  }
  float ob0 = 0.f, ob1 = 0.f;
#pragma unroll 4
  for (int j = 0; j < kN; ++j) {
    uint4 m = *(const uint4*)&Mlds[j * kMstride + b * 8];  // 16-lane broadcast
    float mj[8];
    unpack8(m, mj);
    float n0 = 0.f, n1 = 0.f;
#pragma unroll
    for (int c = 0; c < 8; ++c) {
      n0 += fabsf(mi[0][c] - mj[c]);
      n1 += fabsf(mi[1][c] - mj[c]);
    }
    ob0 += __expf(-n0);
    ob1 += __expf(-n1);
  }
  obuf[i0 * kOstride + b] = ob0;
  obuf[(i0 + 1) * kOstride + b] = ob1;
  __syncthreads();

  // Phase 3c: coalesced o_b stores (32 n x 4 float4 per block).
  if (tid < 128) {
    const int n = tid >> 2;
    const int b4 = tid & 3;
    float4 v = *(const float4*)&obuf[n * kOstride + b4 * 4];
    out4[(size_t)(n * kHW + hw) * (kOutRow / 4) + (kF / 4) + qg * 4 + b4] = v;
  }
}

extern "C" void kernel_launch(void* const* d_in, const int* in_sizes, int n_in,
                              void* d_out, int out_size, void* d_ws, size_t ws_size,
                              hipStream_t stream) {
  const float* x = (const float*)d_in[0];     // [32,16,16,256]
  const float* T = (const float*)d_in[1];     // [256,64,8] = [256][512]
  float* out = (float*)d_out;                 // [32,16,16,320]
  (void)in_sizes; (void)n_in; (void)out_size; (void)d_ws; (void)ws_size;
  mbd_fused<<<dim3(4 * kHW), dim3(256), 0, stream>>>(x, T, out);
}

// Round 8
// 79.364 us; speedup vs baseline: 1.2137x; 1.2137x over previous
//
#include <hip/hip_runtime.h>
#include <hip/hip_bf16.h>

// MiniBatchDiscrimination via bf16 MFMA (gfx950), prep + lean main kernel.
// x: [32,16,16,256] f32, T: [256,64,8] f32, out: [32,16,16,320] f32.
// prep (grid 320): blocks 0..255 pack x -> A-fragments xf[hw][1024] (bf16)
//   and do the f32 passthrough x->out; blocks 256..319 pack T -> Tf frags.
// mbd_main (grid 2048 = pixel x t-eighth, 256 thr, 4 blocks/CU):
//   24 coalesced uint4 loads (xf, Tf from L2) -> 16 MFMA -> park M in 4.5 KB
//   LDS -> one barrier -> pairwise exp(-L1) (1 task/thread) -> coalesced
//   o_b stores. No staging LDS, no pre-MFMA barrier.

namespace {
constexpr int kN = 32;
constexpr int kHW = 256;
constexpr int kF = 256;          // GEMM K
constexpr int kOutRow = 320;
constexpr int kMstride = 72;     // ushorts/row: 64 + 8 pad (144 B)
constexpr int kOstride = 12;     // floats/row in obuf
constexpr int kXfFrags = 1024;   // uint4 frags per pixel (2 rt x 8 kt x 64 lanes)
}

using frag_ab = __attribute__((ext_vector_type(8))) short;   // 8 bf16
using frag_cd = __attribute__((ext_vector_type(4))) float;   // 4 f32

__device__ inline unsigned short f2bf(float f) {
  union { __hip_bfloat16 h; unsigned short u; } c;
  c.h = __float2bfloat16(f);
  return c.u;
}

__device__ inline uint4 pack_bf8(const float4& v0, const float4& v1) {
  uint4 p;
  p.x = (unsigned)f2bf(v0.x) | ((unsigned)f2bf(v0.y) << 16);
  p.y = (unsigned)f2bf(v0.z) | ((unsigned)f2bf(v0.w) << 16);
  p.z = (unsigned)f2bf(v1.x) | ((unsigned)f2bf(v1.y) << 16);
  p.w = (unsigned)f2bf(v1.z) | ((unsigned)f2bf(v1.w) << 16);
  return p;
}

__device__ inline void unpack8(const uint4& m, float* f) {
  f[0] = __uint_as_float(m.x << 16);  f[1] = __uint_as_float(m.x & 0xffff0000u);
  f[2] = __uint_as_float(m.y << 16);  f[3] = __uint_as_float(m.y & 0xffff0000u);
  f[4] = __uint_as_float(m.z << 16);  f[5] = __uint_as_float(m.z & 0xffff0000u);
  f[6] = __uint_as_float(m.w << 16);  f[7] = __uint_as_float(m.w & 0xffff0000u);
}

// ---- Kernel 1: prep (x->A-frags + passthrough; T->B-frags) ----
__global__ __launch_bounds__(256)
void prep(const float* __restrict__ x, const float* __restrict__ T,
          float* __restrict__ out, uint4* __restrict__ xf,
          uint4* __restrict__ Tf) {
  const int tid = threadIdx.x;
  if (blockIdx.x < 256) {
    const int hw = blockIdx.x;
    const int l = tid & 63, w = tid >> 6;
#pragma unroll
    for (int it = 0; it < 4; ++it) {
      const int fg = it * 4 + w;               // 0..15 = rt*8 + kt
      const int rt = fg >> 3, kt = fg & 7;
      const int n = rt * 16 + (l & 15);
      const int k0 = kt * 32 + (l >> 4) * 8;
      const float* xp = x + ((size_t)(n * kHW + hw) * kF + k0);
      float4 v0 = *(const float4*)xp;
      float4 v1 = *(const float4*)(xp + 4);
      float* op = out + ((size_t)(n * kHW + hw) * kOutRow + k0);
      *(float4*)op = v0;                       // passthrough
      *(float4*)(op + 4) = v1;
      xf[(size_t)hw * kXfFrags + fg * 64 + l] = pack_bf8(v0, v1);
    }
  } else {
    const int g = (blockIdx.x - 256) * 256 + tid;  // 0..16383
    const int l = g & 63;
    const int frag = g >> 6;                   // 0..255 = tt*8 + kt
    const int tt = frag >> 3, kt = frag & 7;
    const int col = tt * 16 + (l & 15);
    const int k0 = kt * 32 + (l >> 4) * 8;
    unsigned p[4];
#pragma unroll
    for (int jj = 0; jj < 4; ++jj) {
      float a = T[(size_t)(k0 + jj * 2) * 512 + col];
      float b = T[(size_t)(k0 + jj * 2 + 1) * 512 + col];
      p[jj] = (unsigned)f2bf(a) | ((unsigned)f2bf(b) << 16);
    }
    Tf[g] = make_uint4(p[0], p[1], p[2], p[3]);
  }
}

// ---- Kernel 2: lean main — MFMA + pairwise ----
__global__ __launch_bounds__(256, 4)
void mbd_main(const uint4* __restrict__ xf, const uint4* __restrict__ Tf,
              float* __restrict__ out) {
  __shared__ __align__(16) unsigned short Mlds[kN * kMstride];  // 4.5 KB
  __shared__ float obuf[kN * kOstride];                         // 1.5 KB
  const int hw = blockIdx.x & (kHW - 1);
  const int g = blockIdx.x >> 8;           // t-eighth 0..7 (8 b's, 64 t-cols)
  const int tid = threadIdx.x;
  const int l = tid & 63, w = tid >> 6;
  const int tT = g * 4 + w;                // global t-tile 0..31

  // All fragment loads issued up-front (independent; one vmcnt batch, L2-hot).
  uint4 Bf[8], Af[2][8];
#pragma unroll
  for (int kt = 0; kt < 8; ++kt) Bf[kt] = Tf[(tT * 8 + kt) * 64 + l];
#pragma unroll
  for (int rt = 0; rt < 2; ++rt)
#pragma unroll
    for (int kt = 0; kt < 8; ++kt)
      Af[rt][kt] = xf[(size_t)hw * kXfFrags + (rt * 8 + kt) * 64 + l];

  frag_cd acc[2] = {};                     // [rt]; D row = n-local, col = t-local
#pragma unroll
  for (int kt = 0; kt < 8; ++kt) {
    frag_ab bf = __builtin_bit_cast(frag_ab, Bf[kt]);
    acc[0] = __builtin_amdgcn_mfma_f32_16x16x32_bf16(
        __builtin_bit_cast(frag_ab, Af[0][kt]), bf, acc[0], 0, 0, 0);
    acc[1] = __builtin_amdgcn_mfma_f32_16x16x32_bf16(
        __builtin_bit_cast(frag_ab, Af[1][kt]), bf, acc[1], 0, 0, 0);
  }

  // Park M (bf16): n = rt*16 + (l>>4)*4 + r, t_local = w*16 + (l&15).
#pragma unroll
  for (int rt = 0; rt < 2; ++rt)
#pragma unroll
    for (int r = 0; r < 4; ++r) {
      const int n = rt * 16 + (l >> 4) * 4 + r;
      const int t = w * 16 + (l & 15);
      Mlds[n * kMstride + t] = f2bf(acc[rt][r]);
    }
  __syncthreads();

  // Pairwise exp(-L1): thread = (b = tid>>5 in 0..7, i = tid&31); 32-j loop.
  const int b = tid >> 5;
  const int i = tid & 31;
  float mi[8];
  {
    uint4 m = *(const uint4*)&Mlds[i * kMstride + b * 8];
    unpack8(m, mi);
  }
  float ob = 0.f;
#pragma unroll 8
  for (int j = 0; j < kN; ++j) {
    uint4 m = *(const uint4*)&Mlds[j * kMstride + b * 8];  // broadcast
    float mj[8];
    unpack8(m, mj);
    float nrm = 0.f;
#pragma unroll
    for (int c = 0; c < 8; ++c) nrm += fabsf(mi[c] - mj[c]);
    ob += __expf(-nrm);
  }
  obuf[i * kOstride + b] = ob;
  __syncthreads();

  // Coalesced o_b stores: 32 n x 2 float4 (this eighth's 8 b's).
  if (tid < 64) {
    const int n = tid >> 1;
    const int b4 = tid & 1;
    float4 v = *(const float4*)&obuf[n * kOstride + b4 * 4];
    *(float4*)&out[(size_t)(n * kHW + hw) * kOutRow + kF + g * 8 + b4 * 4] = v;
  }
}

extern "C" void kernel_launch(void* const* d_in, const int* in_sizes, int n_in,
                              void* d_out, int out_size, void* d_ws, size_t ws_size,
                              hipStream_t stream) {
  const float* x = (const float*)d_in[0];     // [32,16,16,256]
  const float* T = (const float*)d_in[1];     // [256,64,8] = [256][512]
  float* out = (float*)d_out;                 // [32,16,16,320]
  uint4* xf = (uint4*)d_ws;                   // 4 MB A-fragments
  uint4* Tf = (uint4*)d_ws + (size_t)kHW * kXfFrags;  // 256 KB B-fragments
  (void)in_sizes; (void)n_in; (void)out_size; (void)ws_size;
  prep<<<dim3(320), dim3(256), 0, stream>>>(x, T, out, xf, Tf);
  mbd_main<<<dim3(8 * kHW), dim3(256), 0, stream>>>(xf, Tf, out);
}

// Round 9
// 78.732 us; speedup vs baseline: 1.2234x; 1.0080x over previous
//
#include <hip/hip_runtime.h>
#include <hip/hip_bf16.h>

// MiniBatchDiscrimination via bf16 MFMA (gfx950), prep + lean main.
// x: [32,16,16,256] f32, T: [256,64,8] f32, out: [32,16,16,320] f32.
// prep (grid 320): blocks 0..255 pack x -> A-frags xf[hw][1024] (bf16) and do
//   the full f32 passthrough; blocks 256..319 pack T -> Tf B-frags.
// mbd_main (grid 1024 = pixel x t-quarter, 256 thr, 4 blocks/CU = ONE resident
//   round): prefetch Bf[2][8] from Tf, stream Af from xf (L2-hot), 32 MFMA,
//   park M quarter in LDS, one barrier, pairwise exp(-L1), coalesced stores.

namespace {
constexpr int kN = 32;
constexpr int kHW = 256;
constexpr int kF = 256;          // GEMM K
constexpr int kOutRow = 320;
constexpr int kMstride = 136;    // ushorts/row: 128 + 8 pad
constexpr int kOstride = 24;     // floats/row in obuf
constexpr int kXfFrags = 1024;   // uint4 frags per pixel (2 rt x 8 kt x 64 lanes)
}

using frag_ab = __attribute__((ext_vector_type(8))) short;   // 8 bf16
using frag_cd = __attribute__((ext_vector_type(4))) float;   // 4 f32

__device__ inline unsigned short f2bf(float f) {
  union { __hip_bfloat16 h; unsigned short u; } c;
  c.h = __float2bfloat16(f);
  return c.u;
}

__device__ inline uint4 pack_bf8(const float4& v0, const float4& v1) {
  uint4 p;
  p.x = (unsigned)f2bf(v0.x) | ((unsigned)f2bf(v0.y) << 16);
  p.y = (unsigned)f2bf(v0.z) | ((unsigned)f2bf(v0.w) << 16);
  p.z = (unsigned)f2bf(v1.x) | ((unsigned)f2bf(v1.y) << 16);
  p.w = (unsigned)f2bf(v1.z) | ((unsigned)f2bf(v1.w) << 16);
  return p;
}

__device__ inline void unpack8(const uint4& m, float* f) {
  f[0] = __uint_as_float(m.x << 16);  f[1] = __uint_as_float(m.x & 0xffff0000u);
  f[2] = __uint_as_float(m.y << 16);  f[3] = __uint_as_float(m.y & 0xffff0000u);
  f[4] = __uint_as_float(m.z << 16);  f[5] = __uint_as_float(m.z & 0xffff0000u);
  f[6] = __uint_as_float(m.w << 16);  f[7] = __uint_as_float(m.w & 0xffff0000u);
}

// ---- Kernel 1: prep (x->A-frags + passthrough; T->B-frags) [R8, verified] ----
__global__ __launch_bounds__(256)
void prep(const float* __restrict__ x, const float* __restrict__ T,
          float* __restrict__ out, uint4* __restrict__ xf,
          uint4* __restrict__ Tf) {
  const int tid = threadIdx.x;
  if (blockIdx.x < 256) {
    const int hw = blockIdx.x;
    const int l = tid & 63, w = tid >> 6;
#pragma unroll
    for (int it = 0; it < 4; ++it) {
      const int fg = it * 4 + w;               // 0..15 = rt*8 + kt
      const int rt = fg >> 3, kt = fg & 7;
      const int n = rt * 16 + (l & 15);
      const int k0 = kt * 32 + (l >> 4) * 8;
      const float* xp = x + ((size_t)(n * kHW + hw) * kF + k0);
      float4 v0 = *(const float4*)xp;
      float4 v1 = *(const float4*)(xp + 4);
      float* op = out + ((size_t)(n * kHW + hw) * kOutRow + k0);
      *(float4*)op = v0;                       // passthrough
      *(float4*)(op + 4) = v1;
      xf[(size_t)hw * kXfFrags + fg * 64 + l] = pack_bf8(v0, v1);
    }
  } else {
    const int g = (blockIdx.x - 256) * 256 + tid;  // 0..16383
    const int l = g & 63;
    const int frag = g >> 6;                   // 0..255 = tt*8 + kt
    const int tt = frag >> 3, kt = frag & 7;
    const int col = tt * 16 + (l & 15);
    const int k0 = kt * 32 + (l >> 4) * 8;
    unsigned p[4];
#pragma unroll
    for (int jj = 0; jj < 4; ++jj) {
      float a = T[(size_t)(k0 + jj * 2) * 512 + col];
      float b = T[(size_t)(k0 + jj * 2 + 1) * 512 + col];
      p[jj] = (unsigned)f2bf(a) | ((unsigned)f2bf(b) << 16);
    }
    Tf[g] = make_uint4(p[0], p[1], p[2], p[3]);
  }
}

// ---- Kernel 2: lean main — quarter-split, one resident round ----
__global__ __launch_bounds__(256, 4)
void mbd_main(const uint4* __restrict__ xf, const uint4* __restrict__ Tf,
              float* __restrict__ out) {
  __shared__ __align__(16) unsigned short Mlds[kN * kMstride];  // 8.7 KB
  __shared__ float obuf[kN * kOstride];                         // 3 KB
  const int hw = blockIdx.x & (kHW - 1);
  const int qg = blockIdx.x >> 8;          // t-quarter 0..3 (16 b's, 128 t-cols)
  const int tid = threadIdx.x;
  const int l = tid & 63, w = tid >> 6;    // 4 waves

  // Prefetch this wave's B-fragments (L2-hot; one vmcnt batch).
  uint4 Bf[2][8];
#pragma unroll
  for (int q = 0; q < 2; ++q) {
    const int tT = qg * 8 + w * 2 + q;     // global t-tile 0..31
#pragma unroll
    for (int kt = 0; kt < 8; ++kt) Bf[q][kt] = Tf[(tT * 8 + kt) * 64 + l];
  }

  // MFMA loop; Af streamed from xf (2 coalesced uint4 per kt, L2-hot).
  const uint4* xfp = xf + (size_t)hw * kXfFrags + l;
  frag_cd acc[2][2] = {};                  // [q][rt]
#pragma unroll
  for (int kt = 0; kt < 8; ++kt) {
    uint4 a0 = xfp[(0 * 8 + kt) * 64];
    uint4 a1 = xfp[(1 * 8 + kt) * 64];
    frag_ab af0 = __builtin_bit_cast(frag_ab, a0);
    frag_ab af1 = __builtin_bit_cast(frag_ab, a1);
#pragma unroll
    for (int q = 0; q < 2; ++q) {
      frag_ab bf = __builtin_bit_cast(frag_ab, Bf[q][kt]);
      acc[q][0] = __builtin_amdgcn_mfma_f32_16x16x32_bf16(af0, bf, acc[q][0], 0, 0, 0);
      acc[q][1] = __builtin_amdgcn_mfma_f32_16x16x32_bf16(af1, bf, acc[q][1], 0, 0, 0);
    }
  }

  // Park M quarter (bf16). C/D: col = l&15 (t), row = (l>>4)*4 + r (n).
#pragma unroll
  for (int q = 0; q < 2; ++q)
#pragma unroll
    for (int rt = 0; rt < 2; ++rt)
#pragma unroll
      for (int r = 0; r < 4; ++r) {
        const int n = rt * 16 + (l >> 4) * 4 + r;
        const int t = (w * 2 + q) * 16 + (l & 15);  // local col 0..127
        Mlds[n * kMstride + t] = f2bf(acc[q][rt][r]);
      }
  __syncthreads();

  // Pairwise exp(-L1). Thread: local b = tid>>4 (0..15), i in {i0, i0+1}.
  const int b = tid >> 4;
  const int i0 = (tid & 15) * 2;
  float mi[2][8];
#pragma unroll
  for (int ii = 0; ii < 2; ++ii) {
    uint4 m = *(const uint4*)&Mlds[(i0 + ii) * kMstride + b * 8];
    unpack8(m, mi[ii]);
  }
  float ob0 = 0.f, ob1 = 0.f;
#pragma unroll 4
  for (int j = 0; j < kN; ++j) {
    uint4 m = *(const uint4*)&Mlds[j * kMstride + b * 8];  // 16-lane broadcast
    float mj[8];
    unpack8(m, mj);
    float n0 = 0.f, n1 = 0.f;
#pragma unroll
    for (int c = 0; c < 8; ++c) {
      n0 += fabsf(mi[0][c] - mj[c]);
      n1 += fabsf(mi[1][c] - mj[c]);
    }
    ob0 += __expf(-n0);
    ob1 += __expf(-n1);
  }
  obuf[i0 * kOstride + b] = ob0;
  obuf[(i0 + 1) * kOstride + b] = ob1;
  __syncthreads();

  // Coalesced o_b stores (32 n x 4 float4 per block).
  if (tid < 128) {
    const int n = tid >> 2;
    const int b4 = tid & 3;
    float4 v = *(const float4*)&obuf[n * kOstride + b4 * 4];
    *(float4*)&out[(size_t)(n * kHW + hw) * kOutRow + kF + qg * 16 + b4 * 4] = v;
  }
}

extern "C" void kernel_launch(void* const* d_in, const int* in_sizes, int n_in,
                              void* d_out, int out_size, void* d_ws, size_t ws_size,
                              hipStream_t stream) {
  const float* x = (const float*)d_in[0];     // [32,16,16,256]
  const float* T = (const float*)d_in[1];     // [256,64,8] = [256][512]
  float* out = (float*)d_out;                 // [32,16,16,320]
  uint4* xf = (uint4*)d_ws;                   // 4 MB A-fragments
  uint4* Tf = (uint4*)d_ws + (size_t)kHW * kXfFrags;  // 256 KB B-fragments
  (void)in_sizes; (void)n_in; (void)out_size; (void)ws_size;
  prep<<<dim3(320), dim3(256), 0, stream>>>(x, T, out, xf, Tf);
  mbd_main<<<dim3(4 * kHW), dim3(256), 0, stream>>>(xf, Tf, out);
}